// Round 4
// baseline (120.482 us; speedup 1.0000x reference)
//
#include <hip/hip_runtime.h>
#include <math.h>

#define NB 128        // batch
#define N 256         // FFT size / image dim
#define NBINS 181
#define THRESH 90
#define RS 136        // row stride (float2) of intermediate F
#define GS 264        // LDS group stride (float2): 528*g mod 32 in {0,16} -> worst 2-way (free)

__device__ __forceinline__ int br4(int i) {
    return ((i&1)<<3) | ((i&2)<<1) | ((i&4)>>1) | ((i&8)>>3);
}

// W16^e = exp(-2*pi*i*e/16), e = 0..7
__device__ const float TW16R[8] = { 1.f,  0.92387953f,  0.70710678f,  0.38268343f,
                                    0.f, -0.38268343f, -0.70710678f, -0.92387953f };
__device__ const float TW16I[8] = { 0.f, -0.38268343f, -0.70710678f, -0.92387953f,
                                   -1.f, -0.92387953f, -0.70710678f, -0.38268343f };

// W256^l = exp(-2*pi*i*l/256), l = 0..15
__device__ const float W256R[16] = {
    1.00000000f, 0.99969882f, 0.99879546f, 0.99729046f, 0.99518473f, 0.99247953f,
    0.98917651f, 0.98527764f, 0.98078528f, 0.97570213f, 0.97003125f, 0.96377607f,
    0.95694034f, 0.94952818f, 0.94154407f, 0.93299280f };
__device__ const float W256I[16] = {
    -0.00000000f, -0.02454123f, -0.04906767f, -0.07356456f, -0.09801714f, -0.12241068f,
    -0.14673047f, -0.17096189f, -0.19509032f, -0.21910124f, -0.24298018f, -0.26671276f,
    -0.29028468f, -0.31368174f, -0.33688985f, -0.35989504f };

// 16-pt DIT FFT, input in BIT-REVERSED order, output natural order. All registers.
__device__ __forceinline__ void fft16(float2 v[16]) {
    #pragma unroll
    for (int s = 0; s < 4; ++s) {
        const int half = 1 << s;
        #pragma unroll
        for (int gg = 0; gg < 16; gg += 2*half) {
            #pragma unroll
            for (int j = 0; j < half; ++j) {
                const float wr = TW16R[j << (3 - s)];
                const float wi = TW16I[j << (3 - s)];
                float2 a = v[gg + j], b = v[gg + j + half];
                float tr = b.x*wr - b.y*wi;
                float ti = b.x*wi + b.y*wr;
                v[gg + j]        = make_float2(a.x + tr, a.y + ti);
                v[gg + j + half] = make_float2(a.x - tr, a.y - ti);
            }
        }
    }
}

// v[k] *= W256^(l*k) via iterated powers (register-only)
__device__ __forceinline__ void twiddle256(float2 v[16], int l) {
    const float c = W256R[l], s = W256I[l];
    float wr = c, wi = s;
    #pragma unroll
    for (int k = 1; k < 16; ++k) {
        float xr = v[k].x, xi = v[k].y;
        v[k] = make_float2(xr*wr - xi*wi, xr*wi + xi*wr);
        float nr = wr*c - wi*s;
        float ni = wr*s + wi*c;
        wr = nr; wi = ni;
    }
}

// ---------------- Row pass: gray + packed-pair register FFT, store k=0..128 ----------------
// grid (8, NB), 256 threads. Block = 16 row pairs; 16 threads per FFT.
__global__ __launch_bounds__(256) void row_fft_kernel(const float* __restrict__ x,
                                                      float2* __restrict__ F) {
    __shared__ float2 zbuf[16*GS];     // 33.8 KB

    const int t = threadIdx.x;
    const int b = blockIdx.y;
    const int pbase = blockIdx.x * 16;

    // ---- staging: grayscale for 16 row pairs, float4 reads, b128 LDS writes ----
    const int cidx = t & 63;
    const int sub  = t >> 6;
    const float* xb = x + (size_t)b * 3 * N * N;
    #pragma unroll
    for (int i = 0; i < 4; ++i) {
        int p  = i*4 + sub;
        int r0 = (pbase + p) * 2;
        const float* p0 = xb + (size_t)r0 * N + cidx*4;
        float4 a0 = *(const float4*)(p0);
        float4 a1 = *(const float4*)(p0 + N*N);
        float4 a2 = *(const float4*)(p0 + 2*N*N);
        float4 b0 = *(const float4*)(p0 + N);
        float4 b1 = *(const float4*)(p0 + N*N + N);
        float4 b2 = *(const float4*)(p0 + 2*N*N + N);
        float gx[4], gy[4];
        #pragma unroll
        for (int j = 0; j < 4; ++j) {
            gx[j] = 0.2989f*((&a0.x)[j]) + 0.587f*((&a1.x)[j]) + 0.114f*((&a2.x)[j]);
            gy[j] = 0.2989f*((&b0.x)[j]) + 0.587f*((&b1.x)[j]) + 0.114f*((&b2.x)[j]);
        }
        *(float4*)&zbuf[p*GS + cidx*4]     = make_float4(gx[0], gy[0], gx[1], gy[1]);
        *(float4*)&zbuf[p*GS + cidx*4 + 2] = make_float4(gx[2], gy[2], gx[3], gy[3]);
    }
    __syncthreads();

    // ---- 256-pt FFT = 16x16 register decomposition ----
    const int g = t >> 4, l = t & 15;
    float2 v[16];
    #pragma unroll
    for (int i = 0; i < 16; ++i) v[i] = zbuf[g*GS + 16*br4(i) + l];
    fft16(v);
    twiddle256(v, l);
    // rotation transpose within group (same wave -> no barrier; 2-way max)
    #pragma unroll
    for (int k = 0; k < 16; ++k) zbuf[g*GS + k*16 + ((l + k) & 15)] = v[k];
    #pragma unroll
    for (int i = 0; i < 16; ++i) v[i] = zbuf[g*GS + l*16 + ((br4(i) + l) & 15)];
    fft16(v);                           // thread l holds Z[l + 16*k2]

    // ---- Hermitian unpack of packed pair (shuffle) + store k=0..128 ----
    const int lane = t & 63;
    const int src  = (lane & 48) | ((16 - l) & 15);
    float2* o0 = F + ((size_t)b * N + (size_t)(pbase + g) * 2) * RS;
    float2* o1 = o0 + RS;
    #pragma unroll
    for (int k2 = 0; k2 < 8; ++k2) {
        float2 zm_s;
        zm_s.x = __shfl(v[15 - k2].x, src, 64);
        zm_s.y = __shfl(v[15 - k2].y, src, 64);
        float2 zm = (l == 0) ? v[(16 - k2) & 15] : zm_s;
        float2 z  = v[k2];
        int k = l + 16*k2;
        o0[k] = make_float2(0.5f*(z.x + zm.x), 0.5f*(z.y - zm.y));
        o1[k] = make_float2(0.5f*(z.y + zm.y), 0.5f*(zm.x - z.x));
    }
    if (l == 0) {
        float2 z = v[8];                // k = 128, self-mirrored
        o0[128] = make_float2(z.x, 0.f);
        o1[128] = make_float2(z.y, 0.f);
    }
}

// ------------- Col pass: direct global->reg FFT + log|F| + mirrored radial binning -------------
// grid (9, NB), 256 threads. 16 columns per block, 16 threads per FFT. No staging LDS.
__global__ __launch_bounds__(256) void col_fft_kernel(const float2* __restrict__ F,
                                                      float* __restrict__ sums) {
    __shared__ float2 sbuf[16*GS];     // transpose only, 33.8 KB
    __shared__ float bins[192];

    const int t = threadIdx.x;
    const int b  = blockIdx.y;
    const int cg = blockIdx.x;         // 0..8
    const int g = t >> 4, l = t & 15;
    const int col = cg*16 + g;
    const bool valid = (col <= 128);

    if (t < 192) bins[t] = 0.0f;
    __syncthreads();

    if (valid) {
        const float2* base = F + (size_t)b * N * RS + col;
        float2 v[16];
        #pragma unroll
        for (int i = 0; i < 16; ++i) v[i] = base[(size_t)(16*br4(i) + l) * RS];
        fft16(v);
        twiddle256(v, l);
        // rotation transpose within group (same wave -> no barrier)
        #pragma unroll
        for (int k = 0; k < 16; ++k) sbuf[g*GS + k*16 + ((l + k) & 15)] = v[k];
        #pragma unroll
        for (int i = 0; i < 16; ++i) v[i] = sbuf[g*GS + l*16 + ((br4(i) + l) & 15)];
        fft16(v);                      // thread l holds X[u = l + 16*k2][col]

        // ---- log|F| + fftshift + radial binning (self + mirror), group-staggered ----
        const float dx  = (float)((col + 128) & 255) - 127.5f;
        const float dxm = (float)((384 - col) & 255) - 127.5f;
        const float dx2 = dx*dx, dxm2 = dxm*dxm;
        const bool mirror = (col >= 1) && (col <= 127);
        #pragma unroll
        for (int kk = 0; kk < 16; ++kk) {
            int k2 = (kk + 4*g) & 15;  // stagger: colliding lanes bin different radii
            int u = l + 16*k2;
            float re = v[k2].x, im = v[k2].y;
            float mag = 0.5f * __logf(re*re + im*im + 1e-16f);
            float dy = (float)((u + 128) & 255) - 127.5f;
            int bin = (int)sqrtf(dx2 + dy*dy);
            atomicAdd(&bins[bin], mag);
            if (mirror) {
                int u2 = (N - u) & 255;
                float dy2 = (float)((u2 + 128) & 255) - 127.5f;
                int bin2 = (int)sqrtf(dxm2 + dy2*dy2);
                atomicAdd(&bins[bin2], mag);
            }
        }
    }
    __syncthreads();
    if (t < NBINS) atomicAdd(&sums[b*NBINS + t], bins[t]);
}

// ------------- Profile: counts, mean, min/max-normalize, dot with w -------------
__global__ __launch_bounds__(256) void profile_kernel(const float* __restrict__ sums,
                                                      const float* __restrict__ w,
                                                      const float* __restrict__ bias,
                                                      float* __restrict__ out) {
    __shared__ int   cnt[192];
    __shared__ float prof[192];
    __shared__ float wred[4][3];

    const int t = threadIdx.x;
    const int b = blockIdx.x;
    if (t < 192) cnt[t] = 0;
    __syncthreads();

    {
        float dy = (float)t - 127.5f;
        for (int xx = 0; xx < 256; ++xx) {
            float dxx = (float)xx - 127.5f;
            int bin = (int)sqrtf(dxx*dxx + dy*dy);
            atomicAdd(&cnt[bin], 1);
        }
    }
    __syncthreads();
    if (t < NBINS) prof[t] = sums[b*NBINS + t] / (float)cnt[t];
    __syncthreads();

    float vv = (t < NBINS) ? prof[t] : prof[0];
    float mn = vv, mx = vv;
    #pragma unroll
    for (int m = 32; m >= 1; m >>= 1) {
        mn = fminf(mn, __shfl_xor(mn, m));
        mx = fmaxf(mx, __shfl_xor(mx, m));
    }
    if ((t & 63) == 0) { wred[t>>6][0] = mn; wred[t>>6][1] = mx; }
    __syncthreads();
    if (t == 0) {
        float a = wred[0][0], z = wred[0][1];
        for (int i = 1; i < 4; ++i) { a = fminf(a, wred[i][0]); z = fmaxf(z, wred[i][1]); }
        wred[0][0] = a; wred[0][1] = z;
    }
    __syncthreads();
    const float mnv = wred[0][0], mxv = wred[0][1];

    float part = 0.0f;
    if (t < THRESH) {
        float f = (prof[(NBINS - THRESH) + t] - mnv) / (mxv - mnv);
        if (f != f) f = 0.0f;          // NaN -> 0
        part = f * w[t];
    }
    #pragma unroll
    for (int m = 32; m >= 1; m >>= 1) part += __shfl_xor(part, m);
    if ((t & 63) == 0) wred[t>>6][2] = part;
    __syncthreads();
    if (t == 0) out[b] = wred[0][2] + wred[1][2] + wred[2][2] + wred[3][2] + bias[0];
}

extern "C" void kernel_launch(void* const* d_in, const int* in_sizes, int n_in,
                              void* d_out, int out_size, void* d_ws, size_t ws_size,
                              hipStream_t stream) {
    const float* x    = (const float*)d_in[0];  // (128,3,256,256)
    const float* w    = (const float*)d_in[1];  // (1,90)
    const float* bias = (const float*)d_in[2];  // (1,)
    float* out = (float*)d_out;                 // (128,1)

    float2* F   = (float2*)d_ws;                // 128*256*136 float2 = 35.65 MB
    float* sums = (float*)((char*)d_ws + (size_t)NB * N * RS * sizeof(float2));

    hipMemsetAsync(sums, 0, (size_t)NB * NBINS * sizeof(float), stream);
    row_fft_kernel<<<dim3(8, NB), 256, 0, stream>>>(x, F);
    col_fft_kernel<<<dim3(9, NB), 256, 0, stream>>>(F, sums);
    profile_kernel<<<NB, 256, 0, stream>>>(sums, w, bias, out);
}

// Round 5
// 119.005 us; speedup vs baseline: 1.0124x; 1.0124x over previous
//
#include <hip/hip_runtime.h>
#include <math.h>

#define NB 128        // batch
#define N 256         // FFT size / image dim
#define NBINS 181
#define THRESH 90
#define RS 136        // row stride (float2) of intermediate F
#define GS 264        // LDS group stride (float2): 528*g mod 32 in {0,16} -> worst 2-way (free)

__device__ __forceinline__ int br4(int i) {
    return ((i&1)<<3) | ((i&2)<<1) | ((i&4)>>1) | ((i&8)>>3);
}

// W16^e = exp(-2*pi*i*e/16), e = 0..7
__device__ const float TW16R[8] = { 1.f,  0.92387953f,  0.70710678f,  0.38268343f,
                                    0.f, -0.38268343f, -0.70710678f, -0.92387953f };
__device__ const float TW16I[8] = { 0.f, -0.38268343f, -0.70710678f, -0.92387953f,
                                   -1.f, -0.92387953f, -0.70710678f, -0.38268343f };

// W256^l = exp(-2*pi*i*l/256), l = 0..15
__device__ const float W256R[16] = {
    1.00000000f, 0.99969882f, 0.99879546f, 0.99729046f, 0.99518473f, 0.99247953f,
    0.98917651f, 0.98527764f, 0.98078528f, 0.97570213f, 0.97003125f, 0.96377607f,
    0.95694034f, 0.94952818f, 0.94154407f, 0.93299280f };
__device__ const float W256I[16] = {
    -0.00000000f, -0.02454123f, -0.04906767f, -0.07356456f, -0.09801714f, -0.12241068f,
    -0.14673047f, -0.17096189f, -0.19509032f, -0.21910124f, -0.24298018f, -0.26671276f,
    -0.29028468f, -0.31368174f, -0.33688985f, -0.35989504f };

// 16-pt DIT FFT, input in BIT-REVERSED order, output natural order. All registers.
__device__ __forceinline__ void fft16(float2 v[16]) {
    #pragma unroll
    for (int s = 0; s < 4; ++s) {
        const int half = 1 << s;
        #pragma unroll
        for (int gg = 0; gg < 16; gg += 2*half) {
            #pragma unroll
            for (int j = 0; j < half; ++j) {
                const float wr = TW16R[j << (3 - s)];
                const float wi = TW16I[j << (3 - s)];
                float2 a = v[gg + j], b = v[gg + j + half];
                float tr = b.x*wr - b.y*wi;
                float ti = b.x*wi + b.y*wr;
                v[gg + j]        = make_float2(a.x + tr, a.y + ti);
                v[gg + j + half] = make_float2(a.x - tr, a.y - ti);
            }
        }
    }
}

// v[k] *= W256^(l*k) via iterated powers (register-only)
__device__ __forceinline__ void twiddle256(float2 v[16], int l) {
    const float c = W256R[l], s = W256I[l];
    float wr = c, wi = s;
    #pragma unroll
    for (int k = 1; k < 16; ++k) {
        float xr = v[k].x, xi = v[k].y;
        v[k] = make_float2(xr*wr - xi*wi, xr*wi + xi*wr);
        float nr = wr*c - wi*s;
        float ni = wr*s + wi*c;
        wr = nr; wi = ni;
    }
}

// ---------------- Row pass: gray + packed-pair register FFT, store k=0..128 ----------------
// grid (16, NB), 128 threads. Block = 8 row pairs; 16 threads per FFT.
__global__ __launch_bounds__(128) void row_fft_kernel(const float* __restrict__ x,
                                                      float2* __restrict__ F) {
    __shared__ float2 zbuf[8*GS];      // 16.9 KB

    const int t = threadIdx.x;
    const int b = blockIdx.y;
    const int pbase = blockIdx.x * 8;

    // ---- staging: grayscale for 8 row pairs, float4 reads, b128 LDS writes ----
    const int cidx = t & 63;
    const int sub  = t >> 6;           // 0..1
    const float* xb = x + (size_t)b * 3 * N * N;
    #pragma unroll
    for (int i = 0; i < 4; ++i) {
        int p  = i*2 + sub;
        int r0 = (pbase + p) * 2;
        const float* p0 = xb + (size_t)r0 * N + cidx*4;
        float4 a0 = *(const float4*)(p0);
        float4 a1 = *(const float4*)(p0 + N*N);
        float4 a2 = *(const float4*)(p0 + 2*N*N);
        float4 b0 = *(const float4*)(p0 + N);
        float4 b1 = *(const float4*)(p0 + N*N + N);
        float4 b2 = *(const float4*)(p0 + 2*N*N + N);
        float gx[4], gy[4];
        #pragma unroll
        for (int j = 0; j < 4; ++j) {
            gx[j] = 0.2989f*((&a0.x)[j]) + 0.587f*((&a1.x)[j]) + 0.114f*((&a2.x)[j]);
            gy[j] = 0.2989f*((&b0.x)[j]) + 0.587f*((&b1.x)[j]) + 0.114f*((&b2.x)[j]);
        }
        *(float4*)&zbuf[p*GS + cidx*4]     = make_float4(gx[0], gy[0], gx[1], gy[1]);
        *(float4*)&zbuf[p*GS + cidx*4 + 2] = make_float4(gx[2], gy[2], gx[3], gy[3]);
    }
    __syncthreads();

    // ---- 256-pt FFT = 16x16 register decomposition ----
    const int g = t >> 4, l = t & 15;  // g 0..7
    float2 v[16];
    #pragma unroll
    for (int i = 0; i < 16; ++i) v[i] = zbuf[g*GS + 16*br4(i) + l];
    fft16(v);
    twiddle256(v, l);
    // rotation transpose within group (same wave -> no barrier; 2-way max)
    #pragma unroll
    for (int k = 0; k < 16; ++k) zbuf[g*GS + k*16 + ((l + k) & 15)] = v[k];
    #pragma unroll
    for (int i = 0; i < 16; ++i) v[i] = zbuf[g*GS + l*16 + ((br4(i) + l) & 15)];
    fft16(v);                           // thread l holds Z[l + 16*k2]

    // ---- Hermitian unpack of packed pair (shuffle) + store k=0..128 ----
    const int lane = t & 63;
    const int src  = (lane & 48) | ((16 - l) & 15);
    float2* o0 = F + ((size_t)b * N + (size_t)(pbase + g) * 2) * RS;
    float2* o1 = o0 + RS;
    #pragma unroll
    for (int k2 = 0; k2 < 8; ++k2) {
        float2 zm_s;
        zm_s.x = __shfl(v[15 - k2].x, src, 64);
        zm_s.y = __shfl(v[15 - k2].y, src, 64);
        float2 zm = (l == 0) ? v[(16 - k2) & 15] : zm_s;
        float2 z  = v[k2];
        int k = l + 16*k2;
        o0[k] = make_float2(0.5f*(z.x + zm.x), 0.5f*(z.y - zm.y));
        o1[k] = make_float2(0.5f*(z.y + zm.y), 0.5f*(zm.x - z.x));
    }
    if (l == 0) {
        float2 z = v[8];                // k = 128, self-mirrored
        o0[128] = make_float2(z.x, 0.f);
        o1[128] = make_float2(z.y, 0.f);
    }
}

// ------------- Col pass: direct global->reg FFT + log|F| + mirrored radial binning -------------
// grid (17, NB), 128 threads. 8 columns per block, 16 threads per FFT. No staging LDS.
__global__ __launch_bounds__(128) void col_fft_kernel(const float2* __restrict__ F,
                                                      float* __restrict__ sums) {
    __shared__ float2 sbuf[8*GS];      // transpose only, 16.9 KB
    __shared__ float bins[192];

    const int t = threadIdx.x;
    const int b  = blockIdx.y;
    const int cg = blockIdx.x;         // 0..16
    const int g = t >> 4, l = t & 15;  // g 0..7
    const int col = cg*8 + g;
    const bool valid = (col <= 128);

    bins[t] = 0.0f;
    if (t < 64) bins[t + 128] = 0.0f;
    __syncthreads();

    if (valid) {
        const float2* base = F + (size_t)b * N * RS + col;
        float2 v[16];
        #pragma unroll
        for (int i = 0; i < 16; ++i) v[i] = base[(size_t)(16*br4(i) + l) * RS];
        fft16(v);
        twiddle256(v, l);
        // rotation transpose within group (same wave -> no barrier)
        #pragma unroll
        for (int k = 0; k < 16; ++k) sbuf[g*GS + k*16 + ((l + k) & 15)] = v[k];
        #pragma unroll
        for (int i = 0; i < 16; ++i) v[i] = sbuf[g*GS + l*16 + ((br4(i) + l) & 15)];
        fft16(v);                      // thread l holds X[u = l + 16*k2][col]

        // ---- log|F| + fftshift + radial binning (self + mirror), group-staggered ----
        const float dx  = (float)((col + 128) & 255) - 127.5f;
        const float dxm = (float)((384 - col) & 255) - 127.5f;
        const float dx2 = dx*dx, dxm2 = dxm*dxm;
        const bool mirror = (col >= 1) && (col <= 127);
        #pragma unroll
        for (int kk = 0; kk < 16; ++kk) {
            int k2 = (kk + 4*g) & 15;  // stagger: colliding lanes bin different radii
            int u = l + 16*k2;
            float re = v[k2].x, im = v[k2].y;
            float mag = 0.5f * __logf(re*re + im*im + 1e-16f);
            float dy = (float)((u + 128) & 255) - 127.5f;
            int bin = (int)sqrtf(dx2 + dy*dy);
            atomicAdd(&bins[bin], mag);
            if (mirror) {
                int u2 = (N - u) & 255;
                float dy2 = (float)((u2 + 128) & 255) - 127.5f;
                int bin2 = (int)sqrtf(dxm2 + dy2*dy2);
                atomicAdd(&bins[bin2], mag);
            }
        }
    }
    __syncthreads();
    for (int i = t; i < NBINS; i += 128) atomicAdd(&sums[b*NBINS + i], bins[i]);
}

// ------------- Profile: counts, mean, min/max-normalize, dot with w -------------
__global__ __launch_bounds__(256) void profile_kernel(const float* __restrict__ sums,
                                                      const float* __restrict__ w,
                                                      const float* __restrict__ bias,
                                                      float* __restrict__ out) {
    __shared__ int   cnt[192];
    __shared__ float prof[192];
    __shared__ float wred[4][3];

    const int t = threadIdx.x;
    const int b = blockIdx.x;
    if (t < 192) cnt[t] = 0;
    __syncthreads();

    {
        float dy = (float)t - 127.5f;
        for (int xx = 0; xx < 256; ++xx) {
            float dxx = (float)xx - 127.5f;
            int bin = (int)sqrtf(dxx*dxx + dy*dy);
            atomicAdd(&cnt[bin], 1);
        }
    }
    __syncthreads();
    if (t < NBINS) prof[t] = sums[b*NBINS + t] / (float)cnt[t];
    __syncthreads();

    float vv = (t < NBINS) ? prof[t] : prof[0];
    float mn = vv, mx = vv;
    #pragma unroll
    for (int m = 32; m >= 1; m >>= 1) {
        mn = fminf(mn, __shfl_xor(mn, m));
        mx = fmaxf(mx, __shfl_xor(mx, m));
    }
    if ((t & 63) == 0) { wred[t>>6][0] = mn; wred[t>>6][1] = mx; }
    __syncthreads();
    if (t == 0) {
        float a = wred[0][0], z = wred[0][1];
        for (int i = 1; i < 4; ++i) { a = fminf(a, wred[i][0]); z = fmaxf(z, wred[i][1]); }
        wred[0][0] = a; wred[0][1] = z;
    }
    __syncthreads();
    const float mnv = wred[0][0], mxv = wred[0][1];

    float part = 0.0f;
    if (t < THRESH) {
        float f = (prof[(NBINS - THRESH) + t] - mnv) / (mxv - mnv);
        if (f != f) f = 0.0f;          // NaN -> 0
        part = f * w[t];
    }
    #pragma unroll
    for (int m = 32; m >= 1; m >>= 1) part += __shfl_xor(part, m);
    if ((t & 63) == 0) wred[t>>6][2] = part;
    __syncthreads();
    if (t == 0) out[b] = wred[0][2] + wred[1][2] + wred[2][2] + wred[3][2] + bias[0];
}

extern "C" void kernel_launch(void* const* d_in, const int* in_sizes, int n_in,
                              void* d_out, int out_size, void* d_ws, size_t ws_size,
                              hipStream_t stream) {
    const float* x    = (const float*)d_in[0];  // (128,3,256,256)
    const float* w    = (const float*)d_in[1];  // (1,90)
    const float* bias = (const float*)d_in[2];  // (1,)
    float* out = (float*)d_out;                 // (128,1)

    float2* F   = (float2*)d_ws;                // 128*256*136 float2 = 35.65 MB
    float* sums = (float*)((char*)d_ws + (size_t)NB * N * RS * sizeof(float2));

    hipMemsetAsync(sums, 0, (size_t)NB * NBINS * sizeof(float), stream);
    row_fft_kernel<<<dim3(16, NB), 128, 0, stream>>>(x, F);
    col_fft_kernel<<<dim3(17, NB), 128, 0, stream>>>(F, sums);
    profile_kernel<<<NB, 256, 0, stream>>>(sums, w, bias, out);
}